// Round 14
// baseline (174.476 us; speedup 1.0000x reference)
//
#include <hip/hip_runtime.h>
#include <hip/hip_bf16.h>

// Attention block: qkv = x@Wqkv+b; MHA softmax; wavg; out = wavg@Wproj+b.
// B=8, P=1024, D=768, H=12, HD=64. Outputs: [out (8,1024,768), wavg (8,1024,768)] fp32.

typedef __attribute__((ext_vector_type(8))) short short8;
typedef __attribute__((ext_vector_type(4))) float f32x4;

#define MFMA_BF16(a, b, c) __builtin_amdgcn_mfma_f32_16x16x32_bf16((a), (b), (c), 0, 0, 0)

#define NB 8
#define NP 1024
#define ND 768
#define NH 12
#define NHD 64
#define NTOK (NB * NP)         // 8192
#define N3D (3 * ND)           // 2304
#define OUT_HALF (NTOK * ND)   // 6291456
// softmax scale (1/sqrt(64)) * log2(e), folded into Q so P = exp2(S)
#define QSCALE 0.18033688f

__device__ __forceinline__ void gload_lds16(const void* gptr, void* ldsptr) {
  __builtin_amdgcn_global_load_lds(
      (const __attribute__((address_space(1))) unsigned int*)gptr,
      (__attribute__((address_space(3))) unsigned int*)ldsptr, 16, 0, 0);
}

__device__ __forceinline__ unsigned pack_bf16x2(float a, float b) {
  __hip_bfloat162 h = __float22bfloat162_rn(float2{a, b});  // v_cvt_pk_bf16_f32
  return *reinterpret_cast<unsigned*>(&h);                  // a in low 16 bits
}

// LDS byte swizzle: XOR byte bits [6:4] with [9:7]. 16-B-granule preserving
// involution. Verified r6: GEMM conflicts 3.5M -> 0.
__device__ __forceinline__ int swz_g(int b) { return b ^ (((b >> 7) & 7) << 4); }

// ---------------- conversion kernels ----------------

__global__ void k_cvt_x(const float* __restrict__ in, __hip_bfloat16* __restrict__ out) {
  int i = (blockIdx.x * 256 + threadIdx.x) * 8;
  float4 a = *(const float4*)(in + i);
  float4 b = *(const float4*)(in + i + 4);
  union { __hip_bfloat16 h[8]; uint4 u; } r;
  r.h[0] = __float2bfloat16(a.x); r.h[1] = __float2bfloat16(a.y);
  r.h[2] = __float2bfloat16(a.z); r.h[3] = __float2bfloat16(a.w);
  r.h[4] = __float2bfloat16(b.x); r.h[5] = __float2bfloat16(b.y);
  r.h[6] = __float2bfloat16(b.z); r.h[7] = __float2bfloat16(b.w);
  *(uint4*)(out + i) = r.u;
}

// in: [K][N] fp32 row-major -> out: [N][K] bf16 row-major (LDS-tiled transpose)
__global__ void k_cvt_t(const float* __restrict__ in, __hip_bfloat16* __restrict__ out,
                        int K, int N) {
  __shared__ float tile[32][33];
  int k0 = blockIdx.x * 32;
  int n0 = blockIdx.y * 32;
  int r = threadIdx.x >> 5;   // 0..7
  int c = threadIdx.x & 31;   // 0..31
#pragma unroll
  for (int i = 0; i < 4; ++i)
    tile[r + 8 * i][c] = in[(size_t)(k0 + r + 8 * i) * N + n0 + c];
  __syncthreads();
#pragma unroll
  for (int i = 0; i < 4; ++i)
    out[(size_t)(n0 + r + 8 * i) * K + k0 + c] = __float2bfloat16(tile[c][r + 8 * i]);
}

// ---------------- shared GEMM mainloop (r10-verified: 54.2 us qkv) ----------------
// 128x128 tile, BK=64 (12 K-steps), 4 waves. TWO LDS buffers of 32 KB.
// Per K-step: vmcnt(8) -> barrier A -> 16 ds_read_b128 -> lgkmcnt(0) ->
// barrier B -> STAGE(kt+2) into retired buf -> 32 MFMA. Counted vmcnt
// never drained mid-loop; peeled final iteration drains vmcnt(0).

__device__ __forceinline__ void gemm_mainloop(const __hip_bfloat16* __restrict__ A,
                                              const __hip_bfloat16* __restrict__ BT,
                                              int m0, int n0, char* Ls,
                                              f32x4 acc[4][4]) {
  const int tid = threadIdx.x;
  const int wid = tid >> 6, lane = tid & 63;
  const int wm = wid >> 1, wn = wid & 1;
  const int lrow = lane & 15, lk = lane >> 4;
  constexpr int K = 768, NKT = K / 64;   // 12 K-steps

  int aoff[4][2], boff[4][2];
#pragma unroll
  for (int i = 0; i < 4; ++i)
#pragma unroll
    for (int kh = 0; kh < 2; ++kh) {
      aoff[i][kh] = swz_g((wm * 64 + i * 16 + lrow) * 128 + kh * 64 + lk * 16);
      boff[i][kh] = swz_g((wn * 64 + i * 16 + lrow) * 128 + kh * 64 + lk * 16);
    }

#define STAGE_G(kt, bi)                                                  \
  {                                                                      \
    const int k0s = (kt) * 64;                                           \
    char* dst = Ls + (bi) * 32768;                                       \
    _Pragma("unroll")                                                    \
    for (int t = 0; t < 4; ++t) {                                        \
      const int L = t * 4096 + tid * 16;   /* linear dest byte */        \
      const int lb = swz_g(L);             /* logical byte */            \
      const int mr = lb >> 7;              /* tile row (128 B/row) */    \
      const int kk = (lb & 127) >> 1;      /* bf16 col within row */     \
      gload_lds16(A + (size_t)(m0 + mr) * K + k0s + kk, dst + L);        \
      gload_lds16(BT + (size_t)(n0 + mr) * K + k0s + kk,                 \
                  dst + 16384 + L);                                      \
    }                                                                    \
  }

  STAGE_G(0, 0);
  STAGE_G(1, 1);            // 16 loads/thread outstanding

#pragma unroll 2
  for (int kt = 0; kt < NKT - 1; ++kt) {
    asm volatile("s_waitcnt vmcnt(8)" ::: "memory");   // tile kt (own loads) done
    __builtin_amdgcn_s_barrier();                      // A: whole tile kt visible

    const char* buf = Ls + (kt & 1) * 32768;
    short8 af[4][2], bf[4][2];
#pragma unroll
    for (int i = 0; i < 4; ++i)
#pragma unroll
      for (int kh = 0; kh < 2; ++kh) {
        af[i][kh] = *(const short8*)(buf + aoff[i][kh]);
        bf[i][kh] = *(const short8*)(buf + 16384 + boff[i][kh]);
      }

    asm volatile("s_waitcnt lgkmcnt(0)" ::: "memory"); // my reads complete
    __builtin_amdgcn_s_barrier();                      // B: everyone's reads done

    if (kt + 2 < NKT) STAGE_G(kt + 2, kt & 1);         // overwrite tile kt's buf

#pragma unroll
    for (int kh = 0; kh < 2; ++kh)
#pragma unroll
      for (int mi = 0; mi < 4; ++mi)
#pragma unroll
        for (int ni = 0; ni < 4; ++ni)
          acc[mi][ni] = MFMA_BF16(af[mi][kh], bf[ni][kh], acc[mi][ni]);
  }

  asm volatile("s_waitcnt vmcnt(0)" ::: "memory");
  __builtin_amdgcn_s_barrier();
  {
    const char* buf = Ls + ((NKT - 1) & 1) * 32768;
    short8 af[4][2], bf[4][2];
#pragma unroll
    for (int i = 0; i < 4; ++i)
#pragma unroll
      for (int kh = 0; kh < 2; ++kh) {
        af[i][kh] = *(const short8*)(buf + aoff[i][kh]);
        bf[i][kh] = *(const short8*)(buf + 16384 + boff[i][kh]);
      }
#pragma unroll
    for (int kh = 0; kh < 2; ++kh)
#pragma unroll
      for (int mi = 0; mi < 4; ++mi)
#pragma unroll
        for (int ni = 0; ni < 4; ++ni)
          acc[mi][ni] = MFMA_BF16(af[mi][kh], bf[ni][kh], acc[mi][ni]);
  }
#undef STAGE_G
}

// ---------------- QKV GEMM: C[8192][2304] = x@Wqkv + b; scatter to q/k/vT ----------------

__launch_bounds__(256)
__global__ void k_qkv_gemm(const __hip_bfloat16* __restrict__ A,
                           const __hip_bfloat16* __restrict__ BT,
                           const float* __restrict__ bias,
                           __hip_bfloat16* __restrict__ q_ws,   // [96][1024][64], pre-scaled
                           __hip_bfloat16* __restrict__ k_ws,   // [96][1024][64]
                           __hip_bfloat16* __restrict__ v_ws) { // [96][64][1024] (V^T)
  __shared__ char Ls[2 * 32768];
  const int mt = blockIdx.x & 63, nt = blockIdx.x >> 6;
  const int m0 = mt * 128, n0 = nt * 128;
  const int wid = threadIdx.x >> 6, lane = threadIdx.x & 63;
  const int wm = wid >> 1, wn = wid & 1;
  const int lrow = lane & 15, lk = lane >> 4;

  f32x4 acc[4][4] = {};
  gemm_mainloop(A, BT, m0, n0, Ls, acc);

  // each 128-wide N-tile lies entirely within q, k, or v (768 % 128 == 0)
  const int which = n0 / ND;
#pragma unroll
  for (int ni = 0; ni < 4; ++ni) {
    const int n = n0 + wn * 64 + ni * 16 + lrow;
    const float bv = bias[n];
    const int hh = (n % ND) >> 6;
    const int hd = n & 63;
#pragma unroll
    for (int mi = 0; mi < 4; ++mi) {
      const int mbase = m0 + wm * 64 + mi * 16 + lk * 4;
#pragma unroll
      for (int i = 0; i < 4; ++i) {
        const int m = mbase + i;
        const float v = acc[mi][ni][i] + bv;
        const int b = m >> 10, p = m & 1023;
        const int bh = b * NH + hh;
        if (which == 0)      q_ws[((size_t)bh * NP + p) * NHD + hd] = __float2bfloat16(v * QSCALE);
        else if (which == 1) k_ws[((size_t)bh * NP + p) * NHD + hd] = __float2bfloat16(v);
        else                 v_ws[((size_t)bh * NHD + hd) * NP + p] = __float2bfloat16(v);
      }
    }
  }
}

// ---------------- attention: NO K/V LDS staging (L2-resident per head) ----------------
// r13 diagnosis: three structurally different staged variants all pinned at
// ~53.5 us with no pipe >38% -> the per-chunk block-wide barrier/staging
// coupling is the suspected cost, and K/V per head is only 256 KB (L2-hot;
// FETCH showed ~one fetch). Guide common-mistake #7 / m169: staging L2-fit
// data is pure overhead. This version reads K/V fragments DIRECTLY from
// global (L2), keeps only the per-wave pbuf in LDS, and has ZERO barriers
// and ZERO vmcnt drains in the main loop -> waves fully independent.
// 1 block = (bh, 128 q-rows), 4 waves x 32 q-rows (two 16-row groups).
// Swapped QK^T (lane holds P for q-row = lrow, 4 keys); cvt_pk pairs ->
// identity-layout pbuf; PV from V^T rows. XCD-chunked: 12 heads per XCD.

#define KVBLK 64

__launch_bounds__(256)
__global__ void k_attn(const __hip_bfloat16* __restrict__ q_ws,
                       const __hip_bfloat16* __restrict__ k_ws,
                       const __hip_bfloat16* __restrict__ v_ws,  // [bh][64][1024]
                       float* __restrict__ wavg_f32,             // [8][1024][768]
                       __hip_bfloat16* __restrict__ wavg_bf) {
  __shared__ char pbuf_all[4 * 4608];               // 4 waves x 32 rows x 144 B
  const int bid = blockIdx.x;                       // 768 = 96 bh x 8 qb
  const int wg = (bid & 7) * 96 + (bid >> 3);       // XCD-chunk: 96 wgs/XCD
  const int bh = wg >> 3, qb = wg & 7;
  const int tid = threadIdx.x;
  const int wid = tid >> 6, lane = tid & 63;
  const int lrow = lane & 15, lk = lane >> 4;
  const int q0 = qb * 128 + wid * 32;
  char* pbuf = pbuf_all + wid * 4608;

  const __hip_bfloat16* Qb = q_ws + (size_t)bh * NP * NHD;
  const __hip_bfloat16* Kb = k_ws + (size_t)bh * NP * NHD;
  const __hip_bfloat16* Vb = v_ws + (size_t)bh * NHD * NP;

  // Q fragments, two 16-row groups (pre-scaled by QSCALE at QKV epilogue)
  short8 qf[2][2];
#pragma unroll
  for (int g = 0; g < 2; ++g) {
    qf[g][0] = *(const short8*)(Qb + (size_t)(q0 + g * 16 + lrow) * NHD + lk * 8);
    qf[g][1] = *(const short8*)(Qb + (size_t)(q0 + g * 16 + lrow) * NHD + 32 + lk * 8);
  }

  f32x4 acc[2][4] = {};          // [group][hd-tile], 16 q x 16 hd each
  float dsum[2] = {0.f, 0.f};    // per-lane denom partial, q = lrow

  for (int kc = 0; kc < NP / KVBLK; ++kc) {
    const int key0 = kc * KVBLK;

    // swapped QK^T: s[g][kt] = S[key = kt*16 + lk*4 + i][q = g*16 + lrow]
    // K rows read directly from global (L2-hot); frags shared by both groups.
    f32x4 s[2][4];
    __builtin_amdgcn_s_setprio(1);
#pragma unroll
    for (int kt = 0; kt < 4; ++kt) {
      const int row = key0 + kt * 16 + lrow;
      short8 klo = *(const short8*)(Kb + (size_t)row * NHD + lk * 8);
      short8 khi = *(const short8*)(Kb + (size_t)row * NHD + 32 + lk * 8);
      f32x4 z = {0.f, 0.f, 0.f, 0.f};
      s[0][kt] = MFMA_BF16(klo, qf[0][0], z);
      s[0][kt] = MFMA_BF16(khi, qf[0][1], s[0][kt]);
      s[1][kt] = MFMA_BF16(klo, qf[1][0], z);
      s[1][kt] = MFMA_BF16(khi, qf[1][1], s[1][kt]);
    }
    __builtin_amdgcn_s_setprio(0);

    // P = exp2(S); pack key pairs in-lane; write P[q][keys] at identity layout
#pragma unroll
    for (int g = 0; g < 2; ++g)
#pragma unroll
      for (int kt = 0; kt < 4; ++kt) {
        const float p0 = __builtin_amdgcn_exp2f(s[g][kt][0]);
        const float p1 = __builtin_amdgcn_exp2f(s[g][kt][1]);
        const float p2 = __builtin_amdgcn_exp2f(s[g][kt][2]);
        const float p3 = __builtin_amdgcn_exp2f(s[g][kt][3]);
        dsum[g] += (p0 + p1) + (p2 + p3);
        uint2 w;
        w.x = pack_bf16x2(p0, p1);
        w.y = pack_bf16x2(p2, p3);
        *(uint2*)(pbuf + (g * 16 + lrow) * 144 + kt * 32 + lk * 8) = w;
      }

    // PV: A = P[q][key] from per-wave pbuf (same-wave DS ordering -> no
    // barrier needed); B = V^T rows read directly from global.
    __builtin_amdgcn_s_setprio(1);
#pragma unroll
    for (int kh = 0; kh < 2; ++kh) {
      short8 a20 = *(const short8*)(pbuf + lrow * 144 + kh * 64 + lk * 16);
      short8 a21 = *(const short8*)(pbuf + (16 + lrow) * 144 + kh * 64 + lk * 16);
#pragma unroll
      for (int hdt = 0; hdt < 4; ++hdt) {
        short8 vf = *(const short8*)(Vb + (size_t)(hdt * 16 + lrow) * NP +
                                     key0 + kh * 32 + lk * 8);
        acc[0][hdt] = MFMA_BF16(a20, vf, acc[0][hdt]);
        acc[1][hdt] = MFMA_BF16(a21, vf, acc[1][hdt]);
      }
    }
    __builtin_amdgcn_s_setprio(0);
  }

  const int b = bh / NH, hh = bh % NH;
#pragma unroll
  for (int g = 0; g < 2; ++g) {
    // combine the 4 lk-lanes holding q = lrow partials: xor 16, 32
    float ds = dsum[g];
    ds += __shfl_xor(ds, 16);
    ds += __shfl_xor(ds, 32);
    float rd[4];
#pragma unroll
    for (int i = 0; i < 4; ++i) rd[i] = 1.0f / __shfl(ds, lk * 4 + i, 16);

#pragma unroll
    for (int hdt = 0; hdt < 4; ++hdt) {
#pragma unroll
      for (int i = 0; i < 4; ++i) {
        const int qq = q0 + g * 16 + lk * 4 + i;
        const int col = hh * NHD + hdt * 16 + lrow;
        const float val = acc[g][hdt][i] * rd[i];
        const size_t o = ((size_t)b * NP + qq) * ND + col;
        wavg_f32[o] = val;
        wavg_bf[o] = __float2bfloat16(val);
      }
    }
  }
}

// ---------------- proj GEMM: out[8192][768] = wavg@Wproj + b (fp32 out) ----------------

__launch_bounds__(256)
__global__ void k_proj_gemm(const __hip_bfloat16* __restrict__ A,
                            const __hip_bfloat16* __restrict__ BT,
                            const float* __restrict__ bias,
                            float* __restrict__ C) {
  __shared__ char Ls[2 * 32768];
  const int mt = blockIdx.x & 63, nt = blockIdx.x >> 6;
  const int m0 = mt * 128, n0 = nt * 128;
  const int wid = threadIdx.x >> 6, lane = threadIdx.x & 63;
  const int wm = wid >> 1, wn = wid & 1;
  const int lrow = lane & 15, lk = lane >> 4;

  f32x4 acc[4][4] = {};
  gemm_mainloop(A, BT, m0, n0, Ls, acc);

#pragma unroll
  for (int ni = 0; ni < 4; ++ni) {
    const int n = n0 + wn * 64 + ni * 16 + lrow;
    const float bv = bias[n];
#pragma unroll
    for (int mi = 0; mi < 4; ++mi) {
      const int mbase = m0 + wm * 64 + mi * 16 + lk * 4;
#pragma unroll
      for (int i = 0; i < 4; ++i)
        C[(size_t)(mbase + i) * ND + n] = acc[mi][ni][i] + bv;
    }
  }
}

// ---------------- launch ----------------

extern "C" void kernel_launch(void* const* d_in, const int* in_sizes, int n_in,
                              void* d_out, int out_size, void* d_ws, size_t ws_size,
                              hipStream_t stream) {
  const float* x      = (const float*)d_in[0];
  const float* w_qkv  = (const float*)d_in[1];
  const float* b_qkv  = (const float*)d_in[2];
  const float* w_proj = (const float*)d_in[3];
  const float* b_proj = (const float*)d_in[4];
  float* out = (float*)d_out;
  float* wavg_out = out + OUT_HALF;

  char* ws = (char*)d_ws;
  // layout (bytes): x_bf16 / wavg_bf16 share (x dead before wavg written)
  __hip_bfloat16* xbf    = (__hip_bfloat16*)(ws);                 // 12,582,912
  __hip_bfloat16* wqkvT  = (__hip_bfloat16*)(ws + 12582912);      //  3,538,944
  __hip_bfloat16* wprojT = (__hip_bfloat16*)(ws + 16121856);      //  1,179,648
  __hip_bfloat16* q_ws   = (__hip_bfloat16*)(ws + 17301504);      // 12,582,912
  __hip_bfloat16* k_ws   = (__hip_bfloat16*)(ws + 29884416);      // 12,582,912
  __hip_bfloat16* v_ws   = (__hip_bfloat16*)(ws + 42467328);      // 12,582,912
  __hip_bfloat16* wavg_bf = xbf;                                  // total 55,050,240 B

  k_cvt_x<<<NTOK * ND / (256 * 8), 256, 0, stream>>>(x, xbf);
  k_cvt_t<<<dim3(ND / 32, N3D / 32), 256, 0, stream>>>(w_qkv, wqkvT, ND, N3D);
  k_cvt_t<<<dim3(ND / 32, ND / 32), 256, 0, stream>>>(w_proj, wprojT, ND, ND);
  k_qkv_gemm<<<(NTOK / 128) * (N3D / 128), 256, 0, stream>>>(xbf, wqkvT, b_qkv,
                                                             q_ws, k_ws, v_ws);
  k_attn<<<(NP / 128) * (NB * NH), 256, 0, stream>>>(q_ws, k_ws, v_ws, wavg_out, wavg_bf);
  k_proj_gemm<<<(NTOK / 128) * (ND / 128), 256, 0, stream>>>(wavg_bf, wprojT, b_proj, out);
}

// Round 15
// 129.641 us; speedup vs baseline: 1.3458x; 1.3458x over previous
//
#include <hip/hip_runtime.h>
#include <hip/hip_bf16.h>

// Attention block: qkv = x@Wqkv+b; MHA softmax; wavg; out = wavg@Wproj+b.
// B=8, P=1024, D=768, H=12, HD=64. Outputs: [out (8,1024,768), wavg (8,1024,768)] fp32.
// This is the round-8 champion configuration (130.7 us measured) + fused
// weight-transpose launch. r4-r14 established: qkv is at the 2-phase
// structural ceiling (~537 TF; 8 variants within 54-59 us; both 8-phase
// ports regressed); attn is pinned at ~53.5 us across 5 structural
// variants (staging removal = 2x regression, proving the staged form).

typedef __attribute__((ext_vector_type(8))) short short8;
typedef __attribute__((ext_vector_type(4))) float f32x4;

#define MFMA_BF16(a, b, c) __builtin_amdgcn_mfma_f32_16x16x32_bf16((a), (b), (c), 0, 0, 0)

#define NB 8
#define NP 1024
#define ND 768
#define NH 12
#define NHD 64
#define NTOK (NB * NP)         // 8192
#define N3D (3 * ND)           // 2304
#define OUT_HALF (NTOK * ND)   // 6291456
// softmax scale (1/sqrt(64)) * log2(e), folded into Q so P = exp2(S)
#define QSCALE 0.18033688f

__device__ __forceinline__ void gload_lds16(const void* gptr, void* ldsptr) {
  __builtin_amdgcn_global_load_lds(
      (const __attribute__((address_space(1))) unsigned int*)gptr,
      (__attribute__((address_space(3))) unsigned int*)ldsptr, 16, 0, 0);
}

__device__ __forceinline__ unsigned pack_bf16x2(float a, float b) {
  __hip_bfloat162 h = __float22bfloat162_rn(float2{a, b});  // v_cvt_pk_bf16_f32
  return *reinterpret_cast<unsigned*>(&h);                  // a in low 16 bits
}

// GEMM-tile LDS swizzle ([rows][64 B] tiles); involution, XORs byte bits [6:4]
// with [9:7] -> per 16-consecutive-row ds_read_b128 group each bank class is
// hit exactly 2x (free). Verified r6: conflicts 3.5M -> 0.
__device__ __forceinline__ int swz_g(int b) { return b ^ (((b >> 7) & 7) << 4); }

// ---------------- conversion kernels ----------------

__global__ void k_cvt_x(const float* __restrict__ in, __hip_bfloat16* __restrict__ out) {
  int i = (blockIdx.x * 256 + threadIdx.x) * 8;
  float4 a = *(const float4*)(in + i);
  float4 b = *(const float4*)(in + i + 4);
  union { __hip_bfloat16 h[8]; uint4 u; } r;
  r.h[0] = __float2bfloat16(a.x); r.h[1] = __float2bfloat16(a.y);
  r.h[2] = __float2bfloat16(a.z); r.h[3] = __float2bfloat16(a.w);
  r.h[4] = __float2bfloat16(b.x); r.h[5] = __float2bfloat16(b.y);
  r.h[6] = __float2bfloat16(b.z); r.h[7] = __float2bfloat16(b.w);
  *(uint4*)(out + i) = r.u;
}

// Fused transpose-convert for BOTH weights (one launch instead of two):
// blockIdx.y < 72 -> w_qkv [768][2304] -> wqkvT [2304][768]
// else            -> w_proj [768][768] -> wprojT [768][768]
__global__ void k_cvt_w(const float* __restrict__ wqkv, __hip_bfloat16* __restrict__ wqkvT,
                        const float* __restrict__ wproj, __hip_bfloat16* __restrict__ wprojT) {
  __shared__ float tile[32][33];
  const int K = 768;
  const float* in;
  __hip_bfloat16* out;
  int N, n0;
  if (blockIdx.y < 72) { in = wqkv;  out = wqkvT;  N = N3D; n0 = blockIdx.y * 32; }
  else                 { in = wproj; out = wprojT; N = ND;  n0 = (blockIdx.y - 72) * 32; }
  int k0 = blockIdx.x * 32;
  int r = threadIdx.x >> 5;   // 0..7
  int c = threadIdx.x & 31;   // 0..31
#pragma unroll
  for (int i = 0; i < 4; ++i)
    tile[r + 8 * i][c] = in[(size_t)(k0 + r + 8 * i) * N + n0 + c];
  __syncthreads();
#pragma unroll
  for (int i = 0; i < 4; ++i)
    out[(size_t)(n0 + r + 8 * i) * K + k0 + c] = __float2bfloat16(tile[c][r + 8 * i]);
}

// ---------------- shared GEMM mainloop (r8-verified champion) ----------------
// 128x128 tile, BK=32, 4 waves, K=768. THREE LDS buffers (16 KB each),
// depth-2 prefetch with COUNTED vmcnt(4): 2 tiles in flight (8 loads/wave),
// wait vmcnt(4) -> oldest tile landed; s_barrier; issue stage(t+2); ds_read+
// MFMA(t). vmcnt(0) only on the peeled final iteration. swz_g swizzle
// (rule 21: linear LDS dest, inverse-swizzled global src, swizzled ds_read).

__device__ __forceinline__ void gemm_mainloop(const __hip_bfloat16* __restrict__ A,
                                              const __hip_bfloat16* __restrict__ BT,
                                              int m0, int n0, char* Ls,
                                              f32x4 acc[4][4]) {
  const int tid = threadIdx.x;
  const int wid = tid >> 6, lane = tid & 63;
  const int wm = wid >> 1, wn = wid & 1;
  const int lrow = lane & 15, lk = lane >> 4;
  constexpr int K = 768, NKT = K / 32;   // 24 K-steps

  // swizzled, loop-invariant fragment read offsets
  int aoff[4], boff[4];
#pragma unroll
  for (int i = 0; i < 4; ++i) {
    aoff[i] = swz_g((wm * 64 + i * 16 + lrow) * 64 + lk * 16);
    boff[i] = swz_g((wn * 64 + i * 16 + lrow) * 64 + lk * 16);
  }

#define STAGE_G(kt, bi)                                                  \
  {                                                                      \
    const int k0s = (kt) * 32;                                           \
    char* dst = Ls + (bi) * 16384;                                       \
    _Pragma("unroll")                                                    \
    for (int t = 0; t < 2; ++t) {                                        \
      const int L = (tid + t * 256) * 16;  /* linear dest byte */        \
      const int lb = swz_g(L);             /* logical byte for dest L */ \
      const int mr = lb >> 6;              /* tile row (64 B/row) */     \
      const int kk = (lb & 63) >> 1;       /* bf16 col within row */     \
      gload_lds16(A + (size_t)(m0 + mr) * K + k0s + kk,                  \
                  dst + wid * 1024 + t * 4096);                          \
      gload_lds16(BT + (size_t)(n0 + mr) * K + k0s + kk,                 \
                  dst + 8192 + wid * 1024 + t * 4096);                   \
    }                                                                    \
  }

#define COMPUTE_T(kt)                                                          \
  {                                                                            \
    const char* buf = Ls + ((kt) % 3) * 16384;                                 \
    short8 af[4], bf[4];                                                       \
    _Pragma("unroll")                                                          \
    for (int i = 0; i < 4; ++i) {                                              \
      af[i] = *(const short8*)(buf + aoff[i]);                                 \
      bf[i] = *(const short8*)(buf + 8192 + boff[i]);                          \
    }                                                                          \
    _Pragma("unroll")                                                          \
    for (int mi = 0; mi < 4; ++mi)                                             \
      _Pragma("unroll")                                                        \
      for (int ni = 0; ni < 4; ++ni)                                           \
        acc[mi][ni] = MFMA_BF16(af[mi], bf[ni], acc[mi][ni]);                  \
  }

  STAGE_G(0, 0);
  STAGE_G(1, 1);            // 8 loads/wave outstanding

#pragma unroll 3
  for (int kt = 0; kt < NKT - 1; ++kt) {
    asm volatile("s_waitcnt vmcnt(4)" ::: "memory");
    __builtin_amdgcn_s_barrier();
    if (kt + 2 < NKT) STAGE_G(kt + 2, (kt + 2) % 3);
    COMPUTE_T(kt);
  }
  asm volatile("s_waitcnt vmcnt(0)" ::: "memory");
  __builtin_amdgcn_s_barrier();
  COMPUTE_T(NKT - 1);

#undef STAGE_G
#undef COMPUTE_T
}

// ---------------- QKV GEMM: C[8192][2304] = x@Wqkv + b; scatter to q/k/vT ----------------

__launch_bounds__(256)
__global__ void k_qkv_gemm(const __hip_bfloat16* __restrict__ A,
                           const __hip_bfloat16* __restrict__ BT,
                           const float* __restrict__ bias,
                           __hip_bfloat16* __restrict__ q_ws,   // [96][1024][64], pre-scaled
                           __hip_bfloat16* __restrict__ k_ws,   // [96][1024][64]
                           __hip_bfloat16* __restrict__ v_ws) { // [96][64][1024] (V^T)
  __shared__ char Ls[3 * 16384];
  const int mt = blockIdx.x & 63, nt = blockIdx.x >> 6;
  const int m0 = mt * 128, n0 = nt * 128;
  const int wid = threadIdx.x >> 6, lane = threadIdx.x & 63;
  const int wm = wid >> 1, wn = wid & 1;
  const int lrow = lane & 15, lk = lane >> 4;

  f32x4 acc[4][4] = {};
  gemm_mainloop(A, BT, m0, n0, Ls, acc);

  // each 128-wide N-tile lies entirely within q, k, or v (768 % 128 == 0)
  const int which = n0 / ND;
#pragma unroll
  for (int ni = 0; ni < 4; ++ni) {
    const int n = n0 + wn * 64 + ni * 16 + lrow;
    const float bv = bias[n];
    const int hh = (n % ND) >> 6;
    const int hd = n & 63;
#pragma unroll
    for (int mi = 0; mi < 4; ++mi) {
      const int mbase = m0 + wm * 64 + mi * 16 + lk * 4;
#pragma unroll
      for (int i = 0; i < 4; ++i) {
        const int m = mbase + i;
        const float v = acc[mi][ni][i] + bv;
        const int b = m >> 10, p = m & 1023;
        const int bh = b * NH + hh;
        if (which == 0)      q_ws[((size_t)bh * NP + p) * NHD + hd] = __float2bfloat16(v * QSCALE);
        else if (which == 1) k_ws[((size_t)bh * NP + p) * NHD + hd] = __float2bfloat16(v);
        else                 v_ws[((size_t)bh * NHD + hd) * NP + p] = __float2bfloat16(v);
      }
    }
  }
}

// ---------------- attention (r8-verified: 53.4 us) ----------------
// 1 block = (bh, 128 q-rows), 4 waves x 32 q-rows (two 16-row groups/wave).
// K/V chunks (64 keys) double-buffered in LDS (XOR-swizzled, rule 21);
// K-frags and V-frags loaded once per wave, reused by both q-groups.
// Grid = 768 blocks = exact capacity (3/CU); XCD-chunked: each XCD owns 12
// whole heads. Swapped QK^T: lane holds P for q-row = lrow, 4 keys.

#define KVBLK 64

__launch_bounds__(256)
__global__ void k_attn(const __hip_bfloat16* __restrict__ q_ws,
                       const __hip_bfloat16* __restrict__ k_ws,
                       const __hip_bfloat16* __restrict__ v_ws,  // [bh][64][1024]
                       float* __restrict__ wavg_f32,             // [8][1024][768]
                       __hip_bfloat16* __restrict__ wavg_bf) {
  // [2][K 8KB + V^T 8KB] dbuf + 4 waves x 32 rows x 144 B pbuf = 50 KB
  __shared__ char smem[2 * 16384 + 4 * 4608];
  const int bid = blockIdx.x;                       // 768 = 96 bh x 8 qb
  const int wg = (bid & 7) * 96 + (bid >> 3);       // XCD-chunk: 96 wgs/XCD
  const int bh = wg >> 3, qb = wg & 7;
  const int tid = threadIdx.x;
  const int wid = tid >> 6, lane = tid & 63;
  const int lrow = lane & 15, lk = lane >> 4;
  const int q0 = qb * 128 + wid * 32;
  char* pbuf = smem + 32768 + wid * 4608;           // 32 rows x 144 B

  const __hip_bfloat16* Qb = q_ws + (size_t)bh * NP * NHD;
  const __hip_bfloat16* Kb = k_ws + (size_t)bh * NP * NHD;
  const __hip_bfloat16* Vb = v_ws + (size_t)bh * NHD * NP;

  // Q fragments, two 16-row groups (pre-scaled by QSCALE at QKV epilogue)
  short8 qf[2][2];
#pragma unroll
  for (int g = 0; g < 2; ++g) {
    qf[g][0] = *(const short8*)(Qb + (size_t)(q0 + g * 16 + lrow) * NHD + lk * 8);
    qf[g][1] = *(const short8*)(Qb + (size_t)(q0 + g * 16 + lrow) * NHD + 32 + lk * 8);
  }

  f32x4 acc[2][4] = {};          // [group][hd-tile], 16 q x 16 hd each
  float dsum[2] = {0.f, 0.f};    // per-lane denom partial for q = lrow (group g)

#define STAGE(buf, key0)                                                          \
  {                                                                               \
    _Pragma("unroll")                                                             \
    for (int p = 0; p < 2; ++p) {                                                 \
      const int L = p * 4096 + tid * 16;                                          \
      const int r = L >> 7;                                                       \
      const int cb = L & 127;                                                     \
      const int sc = (cb ^ ((r & 7) << 4)) >> 1;  /* swizzled element col */      \
      gload_lds16(Kb + (size_t)((key0) + r) * NHD + sc, (buf) + L);               \
      gload_lds16(Vb + (size_t)r * NP + (key0) + sc, (buf) + 8192 + L);           \
    }                                                                             \
  }

  char* cur = smem;
  char* nxt = smem + 16384;
  STAGE(cur, 0);
  __syncthreads();   // drains vmcnt(0)

  for (int kc = 0; kc < NP / KVBLK; ++kc) {
    if (kc < NP / KVBLK - 1) STAGE(nxt, (kc + 1) * KVBLK);

    char* Ks = cur;
    char* Vs = cur + 8192;

    // swapped QK^T: s[g][kt] = S[key = kt*16 + lk*4 + i][q = g*16 + lrow]
    // K-frags read once, used by both groups.
    f32x4 s[2][4];
    __builtin_amdgcn_s_setprio(1);
#pragma unroll
    for (int kt = 0; kt < 4; ++kt) {
      const int row = kt * 16 + lrow;
      const int sw = (row & 7) << 4;
      short8 klo = *(const short8*)(Ks + row * 128 + ((lk * 16) ^ sw));
      short8 khi = *(const short8*)(Ks + row * 128 + ((64 + lk * 16) ^ sw));
      f32x4 z = {0.f, 0.f, 0.f, 0.f};
      s[0][kt] = MFMA_BF16(klo, qf[0][0], z);
      s[0][kt] = MFMA_BF16(khi, qf[0][1], s[0][kt]);
      s[1][kt] = MFMA_BF16(klo, qf[1][0], z);
      s[1][kt] = MFMA_BF16(khi, qf[1][1], s[1][kt]);
    }
    __builtin_amdgcn_s_setprio(0);

    // P = exp2(S); pack key pairs in-lane; write P[q][keys] at identity layout
#pragma unroll
    for (int g = 0; g < 2; ++g)
#pragma unroll
      for (int kt = 0; kt < 4; ++kt) {
        const float p0 = __builtin_amdgcn_exp2f(s[g][kt][0]);
        const float p1 = __builtin_amdgcn_exp2f(s[g][kt][1]);
        const float p2 = __builtin_amdgcn_exp2f(s[g][kt][2]);
        const float p3 = __builtin_amdgcn_exp2f(s[g][kt][3]);
        dsum[g] += (p0 + p1) + (p2 + p3);
        uint2 w;
        w.x = pack_bf16x2(p0, p1);
        w.y = pack_bf16x2(p2, p3);
        *(uint2*)(pbuf + (g * 16 + lrow) * 144 + kt * 32 + lk * 8) = w;
      }

    // PV: V-frags read once, used by both groups. D[m=q'][n=hd].
    __builtin_amdgcn_s_setprio(1);
#pragma unroll
    for (int kh = 0; kh < 2; ++kh) {
      short8 a20 = *(const short8*)(pbuf + lrow * 144 + kh * 64 + lk * 16);
      short8 a21 = *(const short8*)(pbuf + (16 + lrow) * 144 + kh * 64 + lk * 16);
#pragma unroll
      for (int hdt = 0; hdt < 4; ++hdt) {
        const int row = hdt * 16 + lrow;
        short8 vf = *(const short8*)(Vs + row * 128 +
                                     ((kh * 64 + lk * 16) ^ ((row & 7) << 4)));
        acc[0][hdt] = MFMA_BF16(a20, vf, acc[0][hdt]);
        acc[1][hdt] = MFMA_BF16(a21, vf, acc[1][hdt]);
      }
    }
    __builtin_amdgcn_s_setprio(0);

    __syncthreads();   // drains prefetch vmcnt + readers done before overwrite
    char* t = cur; cur = nxt; nxt = t;
  }

  const int b = bh / NH, hh = bh % NH;
#pragma unroll
  for (int g = 0; g < 2; ++g) {
    // combine the 4 lk-lanes holding q = lrow partials: xor 16, 32
    float ds = dsum[g];
    ds += __shfl_xor(ds, 16);
    ds += __shfl_xor(ds, 32);
    float rd[4];
#pragma unroll
    for (int i = 0; i < 4; ++i) rd[i] = 1.0f / __shfl(ds, lk * 4 + i, 16);

#pragma unroll
    for (int hdt = 0; hdt < 4; ++hdt) {
#pragma unroll
      for (int i = 0; i < 4; ++i) {
        const int qq = q0 + g * 16 + lk * 4 + i;
        const int col = hh * NHD + hdt * 16 + lrow;
        const float val = acc[g][hdt][i] * rd[i];
        const size_t o = ((size_t)b * NP + qq) * ND + col;
        wavg_f32[o] = val;
        wavg_bf[o] = __float2bfloat16(val);
      }
    }
  }
#undef STAGE
}

// ---------------- proj GEMM: out[8192][768] = wavg@Wproj + b (fp32 out) ----------------

__launch_bounds__(256)
__global__ void k_proj_gemm(const __hip_bfloat16* __restrict__ A,
                            const __hip_bfloat16* __restrict__ BT,
                            const float* __restrict__ bias,
                            float* __restrict__ C) {
  __shared__ char Ls[3 * 16384];
  const int mt = blockIdx.x & 63, nt = blockIdx.x >> 6;
  const int m0 = mt * 128, n0 = nt * 128;
  const int wid = threadIdx.x >> 6, lane = threadIdx.x & 63;
  const int wm = wid >> 1, wn = wid & 1;
  const int lrow = lane & 15, lk = lane >> 4;

  f32x4 acc[4][4] = {};
  gemm_mainloop(A, BT, m0, n0, Ls, acc);

#pragma unroll
  for (int ni = 0; ni < 4; ++ni) {
    const int n = n0 + wn * 64 + ni * 16 + lrow;
    const float bv = bias[n];
#pragma unroll
    for (int mi = 0; mi < 4; ++mi) {
      const int mbase = m0 + wm * 64 + mi * 16 + lk * 4;
#pragma unroll
      for (int i = 0; i < 4; ++i)
        C[(size_t)(mbase + i) * ND + n] = acc[mi][ni][i] + bv;
    }
  }
}

// ---------------- launch ----------------

extern "C" void kernel_launch(void* const* d_in, const int* in_sizes, int n_in,
                              void* d_out, int out_size, void* d_ws, size_t ws_size,
                              hipStream_t stream) {
  const float* x      = (const float*)d_in[0];
  const float* w_qkv  = (const float*)d_in[1];
  const float* b_qkv  = (const float*)d_in[2];
  const float* w_proj = (const float*)d_in[3];
  const float* b_proj = (const float*)d_in[4];
  float* out = (float*)d_out;
  float* wavg_out = out + OUT_HALF;

  char* ws = (char*)d_ws;
  // layout (bytes): x_bf16 / wavg_bf16 share (x dead before wavg written)
  __hip_bfloat16* xbf    = (__hip_bfloat16*)(ws);                 // 12,582,912
  __hip_bfloat16* wqkvT  = (__hip_bfloat16*)(ws + 12582912);      //  3,538,944
  __hip_bfloat16* wprojT = (__hip_bfloat16*)(ws + 16121856);      //  1,179,648
  __hip_bfloat16* q_ws   = (__hip_bfloat16*)(ws + 17301504);      // 12,582,912
  __hip_bfloat16* k_ws   = (__hip_bfloat16*)(ws + 29884416);      // 12,582,912
  __hip_bfloat16* v_ws   = (__hip_bfloat16*)(ws + 42467328);      // 12,582,912
  __hip_bfloat16* wavg_bf = xbf;                                  // total 55,050,240 B

  k_cvt_x<<<NTOK * ND / (256 * 8), 256, 0, stream>>>(x, xbf);
  k_cvt_w<<<dim3(ND / 32, 96), 256, 0, stream>>>(w_qkv, wqkvT, w_proj, wprojT);
  k_qkv_gemm<<<(NTOK / 128) * (N3D / 128), 256, 0, stream>>>(xbf, wqkvT, b_qkv,
                                                             q_ws, k_ws, v_ws);
  k_attn<<<(NP / 128) * (NB * NH), 256, 0, stream>>>(q_ws, k_ws, v_ws, wavg_out, wavg_bf);
  k_proj_gemm<<<(NTOK / 128) * (ND / 128), 256, 0, stream>>>(wavg_bf, wprojT, b_proj, out);
}

// Round 16
// 126.781 us; speedup vs baseline: 1.3762x; 1.0226x over previous
//
#include <hip/hip_runtime.h>
#include <hip/hip_bf16.h>

// Attention block: qkv = x@Wqkv+b; MHA softmax; wavg; out = wavg@Wproj+b.
// B=8, P=1024, D=768, H=12, HD=64. Outputs: [out (8,1024,768), wavg (8,1024,768)] fp32.
// Round-15 champion (129.6 us) + single fused conversion launch.
// Session ledger: qkv bracketed 54-59 us over 8 schedule variants (2-phase
// structural plateau ~537 TF); attn bracketed 53.4-57 us over 6 variants;
// 256^2-class ports regress on grid quantization (288/576 blocks vs 256 CU).

typedef __attribute__((ext_vector_type(8))) short short8;
typedef __attribute__((ext_vector_type(4))) float f32x4;

#define MFMA_BF16(a, b, c) __builtin_amdgcn_mfma_f32_16x16x32_bf16((a), (b), (c), 0, 0, 0)

#define NB 8
#define NP 1024
#define ND 768
#define NH 12
#define NHD 64
#define NTOK (NB * NP)         // 8192
#define N3D (3 * ND)           // 2304
#define OUT_HALF (NTOK * ND)   // 6291456
// softmax scale (1/sqrt(64)) * log2(e), folded into Q so P = exp2(S)
#define QSCALE 0.18033688f

__device__ __forceinline__ void gload_lds16(const void* gptr, void* ldsptr) {
  __builtin_amdgcn_global_load_lds(
      (const __attribute__((address_space(1))) unsigned int*)gptr,
      (__attribute__((address_space(3))) unsigned int*)ldsptr, 16, 0, 0);
}

__device__ __forceinline__ unsigned pack_bf16x2(float a, float b) {
  __hip_bfloat162 h = __float22bfloat162_rn(float2{a, b});  // v_cvt_pk_bf16_f32
  return *reinterpret_cast<unsigned*>(&h);                  // a in low 16 bits
}

// GEMM-tile LDS swizzle ([rows][64 B] tiles); involution, XORs byte bits [6:4]
// with [9:7] -> per 16-consecutive-row ds_read_b128 group each bank class is
// hit exactly 2x (free). Verified r6: conflicts 3.5M -> 0.
__device__ __forceinline__ int swz_g(int b) { return b ^ (((b >> 7) & 7) << 4); }

// ---------------- fused conversion kernel (one launch) ----------------
// blocks [0, 3072):      x [8192][768] fp32 -> bf16 flat (8 elem/thread)
// blocks [3072, 4800):   w_qkv [768][2304] -> wqkvT [2304][768] bf16 (transpose)
// blocks [4800, 5376):   w_proj [768][768] -> wprojT [768][768] bf16 (transpose)

__global__ void k_cvt_all(const float* __restrict__ x, __hip_bfloat16* __restrict__ xbf,
                          const float* __restrict__ wqkv, __hip_bfloat16* __restrict__ wqkvT,
                          const float* __restrict__ wproj, __hip_bfloat16* __restrict__ wprojT) {
  __shared__ float tile[32][33];
  int blk = blockIdx.x;
  if (blk < 3072) {
    int i = (blk * 256 + threadIdx.x) * 8;
    float4 a = *(const float4*)(x + i);
    float4 b = *(const float4*)(x + i + 4);
    union { __hip_bfloat16 h[8]; uint4 u; } r;
    r.h[0] = __float2bfloat16(a.x); r.h[1] = __float2bfloat16(a.y);
    r.h[2] = __float2bfloat16(a.z); r.h[3] = __float2bfloat16(a.w);
    r.h[4] = __float2bfloat16(b.x); r.h[5] = __float2bfloat16(b.y);
    r.h[6] = __float2bfloat16(b.z); r.h[7] = __float2bfloat16(b.w);
    *(uint4*)(xbf + i) = r.u;
    return;
  }
  blk -= 3072;
  const int kx = blk % 24;        // K-tile (768/32)
  const int ny = blk / 24;        // N-tile: 0..71 qkv, 72..95 proj
  const float* in;
  __hip_bfloat16* out;
  int N, n0;
  if (ny < 72) { in = wqkv;  out = wqkvT;  N = N3D; n0 = ny * 32; }
  else         { in = wproj; out = wprojT; N = ND;  n0 = (ny - 72) * 32; }
  const int k0 = kx * 32;
  const int r = threadIdx.x >> 5;   // 0..7
  const int c = threadIdx.x & 31;   // 0..31
#pragma unroll
  for (int i = 0; i < 4; ++i)
    tile[r + 8 * i][c] = in[(size_t)(k0 + r + 8 * i) * N + n0 + c];
  __syncthreads();
#pragma unroll
  for (int i = 0; i < 4; ++i)
    out[(size_t)(n0 + r + 8 * i) * 768 + k0 + c] = __float2bfloat16(tile[c][r + 8 * i]);
}

// ---------------- shared GEMM mainloop (r8-verified champion) ----------------
// 128x128 tile, BK=32, 4 waves, K=768. THREE LDS buffers (16 KB each),
// depth-2 prefetch with COUNTED vmcnt(4): 2 tiles in flight (8 loads/wave),
// wait vmcnt(4) -> oldest tile landed; s_barrier; issue stage(t+2); ds_read+
// MFMA(t). vmcnt(0) only on the peeled final iteration. swz_g swizzle
// (rule 21: linear LDS dest, inverse-swizzled global src, swizzled ds_read).

__device__ __forceinline__ void gemm_mainloop(const __hip_bfloat16* __restrict__ A,
                                              const __hip_bfloat16* __restrict__ BT,
                                              int m0, int n0, char* Ls,
                                              f32x4 acc[4][4]) {
  const int tid = threadIdx.x;
  const int wid = tid >> 6, lane = tid & 63;
  const int wm = wid >> 1, wn = wid & 1;
  const int lrow = lane & 15, lk = lane >> 4;
  constexpr int K = 768, NKT = K / 32;   // 24 K-steps

  // swizzled, loop-invariant fragment read offsets
  int aoff[4], boff[4];
#pragma unroll
  for (int i = 0; i < 4; ++i) {
    aoff[i] = swz_g((wm * 64 + i * 16 + lrow) * 64 + lk * 16);
    boff[i] = swz_g((wn * 64 + i * 16 + lrow) * 64 + lk * 16);
  }

#define STAGE_G(kt, bi)                                                  \
  {                                                                      \
    const int k0s = (kt) * 32;                                           \
    char* dst = Ls + (bi) * 16384;                                       \
    _Pragma("unroll")                                                    \
    for (int t = 0; t < 2; ++t) {                                        \
      const int L = (tid + t * 256) * 16;  /* linear dest byte */        \
      const int lb = swz_g(L);             /* logical byte for dest L */ \
      const int mr = lb >> 6;              /* tile row (64 B/row) */     \
      const int kk = (lb & 63) >> 1;       /* bf16 col within row */     \
      gload_lds16(A + (size_t)(m0 + mr) * K + k0s + kk,                  \
                  dst + wid * 1024 + t * 4096);                          \
      gload_lds16(BT + (size_t)(n0 + mr) * K + k0s + kk,                 \
                  dst + 8192 + wid * 1024 + t * 4096);                   \
    }                                                                    \
  }

#define COMPUTE_T(kt)                                                          \
  {                                                                            \
    const char* buf = Ls + ((kt) % 3) * 16384;                                 \
    short8 af[4], bf[4];                                                       \
    _Pragma("unroll")                                                          \
    for (int i = 0; i < 4; ++i) {                                              \
      af[i] = *(const short8*)(buf + aoff[i]);                                 \
      bf[i] = *(const short8*)(buf + 8192 + boff[i]);                          \
    }                                                                          \
    _Pragma("unroll")                                                          \
    for (int mi = 0; mi < 4; ++mi)                                             \
      _Pragma("unroll")                                                        \
      for (int ni = 0; ni < 4; ++ni)                                           \
        acc[mi][ni] = MFMA_BF16(af[mi], bf[ni], acc[mi][ni]);                  \
  }

  STAGE_G(0, 0);
  STAGE_G(1, 1);            // 8 loads/wave outstanding

#pragma unroll 3
  for (int kt = 0; kt < NKT - 1; ++kt) {
    asm volatile("s_waitcnt vmcnt(4)" ::: "memory");
    __builtin_amdgcn_s_barrier();
    if (kt + 2 < NKT) STAGE_G(kt + 2, (kt + 2) % 3);
    COMPUTE_T(kt);
  }
  asm volatile("s_waitcnt vmcnt(0)" ::: "memory");
  __builtin_amdgcn_s_barrier();
  COMPUTE_T(NKT - 1);

#undef STAGE_G
#undef COMPUTE_T
}

// ---------------- QKV GEMM: C[8192][2304] = x@Wqkv + b; scatter to q/k/vT ----------------

__launch_bounds__(256)
__global__ void k_qkv_gemm(const __hip_bfloat16* __restrict__ A,
                           const __hip_bfloat16* __restrict__ BT,
                           const float* __restrict__ bias,
                           __hip_bfloat16* __restrict__ q_ws,   // [96][1024][64], pre-scaled
                           __hip_bfloat16* __restrict__ k_ws,   // [96][1024][64]
                           __hip_bfloat16* __restrict__ v_ws) { // [96][64][1024] (V^T)
  __shared__ char Ls[3 * 16384];
  const int mt = blockIdx.x & 63, nt = blockIdx.x >> 6;
  const int m0 = mt * 128, n0 = nt * 128;
  const int wid = threadIdx.x >> 6, lane = threadIdx.x & 63;
  const int wm = wid >> 1, wn = wid & 1;
  const int lrow = lane & 15, lk = lane >> 4;

  f32x4 acc[4][4] = {};
  gemm_mainloop(A, BT, m0, n0, Ls, acc);

  // each 128-wide N-tile lies entirely within q, k, or v (768 % 128 == 0)
  const int which = n0 / ND;
#pragma unroll
  for (int ni = 0; ni < 4; ++ni) {
    const int n = n0 + wn * 64 + ni * 16 + lrow;
    const float bv = bias[n];
    const int hh = (n % ND) >> 6;
    const int hd = n & 63;
#pragma unroll
    for (int mi = 0; mi < 4; ++mi) {
      const int mbase = m0 + wm * 64 + mi * 16 + lk * 4;
#pragma unroll
      for (int i = 0; i < 4; ++i) {
        const int m = mbase + i;
        const float v = acc[mi][ni][i] + bv;
        const int b = m >> 10, p = m & 1023;
        const int bh = b * NH + hh;
        if (which == 0)      q_ws[((size_t)bh * NP + p) * NHD + hd] = __float2bfloat16(v * QSCALE);
        else if (which == 1) k_ws[((size_t)bh * NP + p) * NHD + hd] = __float2bfloat16(v);
        else                 v_ws[((size_t)bh * NHD + hd) * NP + p] = __float2bfloat16(v);
      }
    }
  }
}

// ---------------- attention (r8-verified: 53.4 us) ----------------
// 1 block = (bh, 128 q-rows), 4 waves x 32 q-rows (two 16-row groups/wave).
// K/V chunks (64 keys) double-buffered in LDS (XOR-swizzled, rule 21);
// K-frags and V-frags loaded once per wave, reused by both q-groups.
// Grid = 768 blocks = exact capacity (3/CU); XCD-chunked: each XCD owns 12
// whole heads. Swapped QK^T: lane holds P for q-row = lrow, 4 keys.

#define KVBLK 64

__launch_bounds__(256)
__global__ void k_attn(const __hip_bfloat16* __restrict__ q_ws,
                       const __hip_bfloat16* __restrict__ k_ws,
                       const __hip_bfloat16* __restrict__ v_ws,  // [bh][64][1024]
                       float* __restrict__ wavg_f32,             // [8][1024][768]
                       __hip_bfloat16* __restrict__ wavg_bf) {
  // [2][K 8KB + V^T 8KB] dbuf + 4 waves x 32 rows x 144 B pbuf = 50 KB
  __shared__ char smem[2 * 16384 + 4 * 4608];
  const int bid = blockIdx.x;                       // 768 = 96 bh x 8 qb
  const int wg = (bid & 7) * 96 + (bid >> 3);       // XCD-chunk: 96 wgs/XCD
  const int bh = wg >> 3, qb = wg & 7;
  const int tid = threadIdx.x;
  const int wid = tid >> 6, lane = tid & 63;
  const int lrow = lane & 15, lk = lane >> 4;
  const int q0 = qb * 128 + wid * 32;
  char* pbuf = smem + 32768 + wid * 4608;           // 32 rows x 144 B

  const __hip_bfloat16* Qb = q_ws + (size_t)bh * NP * NHD;
  const __hip_bfloat16* Kb = k_ws + (size_t)bh * NP * NHD;
  const __hip_bfloat16* Vb = v_ws + (size_t)bh * NHD * NP;

  // Q fragments, two 16-row groups (pre-scaled by QSCALE at QKV epilogue)
  short8 qf[2][2];
#pragma unroll
  for (int g = 0; g < 2; ++g) {
    qf[g][0] = *(const short8*)(Qb + (size_t)(q0 + g * 16 + lrow) * NHD + lk * 8);
    qf[g][1] = *(const short8*)(Qb + (size_t)(q0 + g * 16 + lrow) * NHD + 32 + lk * 8);
  }

  f32x4 acc[2][4] = {};          // [group][hd-tile], 16 q x 16 hd each
  float dsum[2] = {0.f, 0.f};    // per-lane denom partial for q = lrow (group g)

#define STAGE(buf, key0)                                                          \
  {                                                                               \
    _Pragma("unroll")                                                             \
    for (int p = 0; p < 2; ++p) {                                                 \
      const int L = p * 4096 + tid * 16;                                          \
      const int r = L >> 7;                                                       \
      const int cb = L & 127;                                                     \
      const int sc = (cb ^ ((r & 7) << 4)) >> 1;  /* swizzled element col */      \
      gload_lds16(Kb + (size_t)((key0) + r) * NHD + sc, (buf) + L);               \
      gload_lds16(Vb + (size_t)r * NP + (key0) + sc, (buf) + 8192 + L);           \
    }                                                                             \
  }

  char* cur = smem;
  char* nxt = smem + 16384;
  STAGE(cur, 0);
  __syncthreads();   // drains vmcnt(0)

  for (int kc = 0; kc < NP / KVBLK; ++kc) {
    if (kc < NP / KVBLK - 1) STAGE(nxt, (kc + 1) * KVBLK);

    char* Ks = cur;
    char* Vs = cur + 8192;

    // swapped QK^T: s[g][kt] = S[key = kt*16 + lk*4 + i][q = g*16 + lrow]
    // K-frags read once, used by both groups.
    f32x4 s[2][4];
    __builtin_amdgcn_s_setprio(1);
#pragma unroll
    for (int kt = 0; kt < 4; ++kt) {
      const int row = kt * 16 + lrow;
      const int sw = (row & 7) << 4;
      short8 klo = *(const short8*)(Ks + row * 128 + ((lk * 16) ^ sw));
      short8 khi = *(const short8*)(Ks + row * 128 + ((64 + lk * 16) ^ sw));
      f32x4 z = {0.f, 0.f, 0.f, 0.f};
      s[0][kt] = MFMA_BF16(klo, qf[0][0], z);
      s[0][kt] = MFMA_BF16(khi, qf[0][1], s[0][kt]);
      s[1][kt] = MFMA_BF16(klo, qf[1][0], z);
      s[1][kt] = MFMA_BF16(khi, qf[1][1], s[1][kt]);
    }
    __builtin_amdgcn_s_setprio(0);

    // P = exp2(S); pack key pairs in-lane; write P[q][keys] at identity layout
#pragma unroll
    for (int g = 0; g < 2; ++g)
#pragma unroll
      for (int kt = 0; kt < 4; ++kt) {
        const float p0 = __builtin_amdgcn_exp2f(s[g][kt][0]);
        const float p1 = __builtin_amdgcn_exp2f(s[g][kt][1]);
        const float p2 = __builtin_amdgcn_exp2f(s[g][kt][2]);
        const float p3 = __builtin_amdgcn_exp2f(s[g][kt][3]);
        dsum[g] += (p0 + p1) + (p2 + p3);
        uint2 w;
        w.x = pack_bf16x2(p0, p1);
        w.y = pack_bf16x2(p2, p3);
        *(uint2*)(pbuf + (g * 16 + lrow) * 144 + kt * 32 + lk * 8) = w;
      }

    // PV: V-frags read once, used by both groups. D[m=q'][n=hd].
    __builtin_amdgcn_s_setprio(1);
#pragma unroll
    for (int kh = 0; kh < 2; ++kh) {
      short8 a20 = *(const short8*)(pbuf + lrow * 144 + kh * 64 + lk * 16);
      short8 a21 = *(const short8*)(pbuf + (16 + lrow) * 144 + kh * 64 + lk * 16);
#pragma unroll
      for (int hdt = 0; hdt < 4; ++hdt) {
        const int row = hdt * 16 + lrow;
        short8 vf = *(const short8*)(Vs + row * 128 +
                                     ((kh * 64 + lk * 16) ^ ((row & 7) << 4)));
        acc[0][hdt] = MFMA_BF16(a20, vf, acc[0][hdt]);
        acc[1][hdt] = MFMA_BF16(a21, vf, acc[1][hdt]);
      }
    }
    __builtin_amdgcn_s_setprio(0);

    __syncthreads();   // drains prefetch vmcnt + readers done before overwrite
    char* t = cur; cur = nxt; nxt = t;
  }

  const int b = bh / NH, hh = bh % NH;
#pragma unroll
  for (int g = 0; g < 2; ++g) {
    // combine the 4 lk-lanes holding q = lrow partials: xor 16, 32
    float ds = dsum[g];
    ds += __shfl_xor(ds, 16);
    ds += __shfl_xor(ds, 32);
    float rd[4];
#pragma unroll
    for (int i = 0; i < 4; ++i) rd[i] = 1.0f / __shfl(ds, lk * 4 + i, 16);

#pragma unroll
    for (int hdt = 0; hdt < 4; ++hdt) {
#pragma unroll
      for (int i = 0; i < 4; ++i) {
        const int qq = q0 + g * 16 + lk * 4 + i;
        const int col = hh * NHD + hdt * 16 + lrow;
        const float val = acc[g][hdt][i] * rd[i];
        const size_t o = ((size_t)b * NP + qq) * ND + col;
        wavg_f32[o] = val;
        wavg_bf[o] = __float2bfloat16(val);
      }
    }
  }
#undef STAGE
}

// ---------------- proj GEMM: out[8192][768] = wavg@Wproj + b (fp32 out) ----------------

__launch_bounds__(256)
__global__ void k_proj_gemm(const __hip_bfloat16* __restrict__ A,
                            const __hip_bfloat16* __restrict__ BT,
                            const float* __restrict__ bias,
                            float* __restrict__ C) {
  __shared__ char Ls[3 * 16384];
  const int mt = blockIdx.x & 63, nt = blockIdx.x >> 6;
  const int m0 = mt * 128, n0 = nt * 128;
  const int wid = threadIdx.x >> 6, lane = threadIdx.x & 63;
  const int wm = wid >> 1, wn = wid & 1;
  const int lrow = lane & 15, lk = lane >> 4;

  f32x4 acc[4][4] = {};
  gemm_mainloop(A, BT, m0, n0, Ls, acc);

#pragma unroll
  for (int ni = 0; ni < 4; ++ni) {
    const int n = n0 + wn * 64 + ni * 16 + lrow;
    const float bv = bias[n];
#pragma unroll
    for (int mi = 0; mi < 4; ++mi) {
      const int mbase = m0 + wm * 64 + mi * 16 + lk * 4;
#pragma unroll
      for (int i = 0; i < 4; ++i)
        C[(size_t)(mbase + i) * ND + n] = acc[mi][ni][i] + bv;
    }
  }
}

// ---------------- launch ----------------

extern "C" void kernel_launch(void* const* d_in, const int* in_sizes, int n_in,
                              void* d_out, int out_size, void* d_ws, size_t ws_size,
                              hipStream_t stream) {
  const float* x      = (const float*)d_in[0];
  const float* w_qkv  = (const float*)d_in[1];
  const float* b_qkv  = (const float*)d_in[2];
  const float* w_proj = (const float*)d_in[3];
  const float* b_proj = (const float*)d_in[4];
  float* out = (float*)d_out;
  float* wavg_out = out + OUT_HALF;

  char* ws = (char*)d_ws;
  // layout (bytes): x_bf16 / wavg_bf16 share (x dead before wavg written)
  __hip_bfloat16* xbf    = (__hip_bfloat16*)(ws);                 // 12,582,912
  __hip_bfloat16* wqkvT  = (__hip_bfloat16*)(ws + 12582912);      //  3,538,944
  __hip_bfloat16* wprojT = (__hip_bfloat16*)(ws + 16121856);      //  1,179,648
  __hip_bfloat16* q_ws   = (__hip_bfloat16*)(ws + 17301504);      // 12,582,912
  __hip_bfloat16* k_ws   = (__hip_bfloat16*)(ws + 29884416);      // 12,582,912
  __hip_bfloat16* v_ws   = (__hip_bfloat16*)(ws + 42467328);      // 12,582,912
  __hip_bfloat16* wavg_bf = xbf;                                  // total 55,050,240 B

  // fused: x-convert (3072 blocks) + wqkv transpose (1728) + wproj transpose (576)
  k_cvt_all<<<3072 + 24 * 96, 256, 0, stream>>>(x, xbf, w_qkv, wqkvT, w_proj, wprojT);
  k_qkv_gemm<<<(NTOK / 128) * (N3D / 128), 256, 0, stream>>>(xbf, wqkvT, b_qkv,
                                                             q_ws, k_ws, v_ws);
  k_attn<<<(NP / 128) * (NB * NH), 256, 0, stream>>>(q_ws, k_ws, v_ws, wavg_out, wavg_bf);
  k_proj_gemm<<<(NTOK / 128) * (ND / 128), 256, 0, stream>>>(wavg_bf, wprojT, b_proj, out);
}

// Round 17
// 125.258 us; speedup vs baseline: 1.3929x; 1.0122x over previous
//
#include <hip/hip_runtime.h>
#include <hip/hip_bf16.h>

// Attention block: qkv = x@Wqkv+b; MHA softmax; wavg; out = wavg@Wproj+b.
// B=8, P=1024, D=768, H=12, HD=64. Outputs: [out (8,1024,768), wavg (8,1024,768)] fp32.
// r16 (126.8 us) with the GEMM mainloop swapped back to the r10/r12-verified
// BK=64 two-barrier form (qkv measured 54.0-54.2 there vs 58.5 for the BK=32
// variant shipped in r14-r16 by mistake). Everything else identical to r16.

typedef __attribute__((ext_vector_type(8))) short short8;
typedef __attribute__((ext_vector_type(4))) float f32x4;

#define MFMA_BF16(a, b, c) __builtin_amdgcn_mfma_f32_16x16x32_bf16((a), (b), (c), 0, 0, 0)

#define NB 8
#define NP 1024
#define ND 768
#define NH 12
#define NHD 64
#define NTOK (NB * NP)         // 8192
#define N3D (3 * ND)           // 2304
#define OUT_HALF (NTOK * ND)   // 6291456
// softmax scale (1/sqrt(64)) * log2(e), folded into Q so P = exp2(S)
#define QSCALE 0.18033688f

__device__ __forceinline__ void gload_lds16(const void* gptr, void* ldsptr) {
  __builtin_amdgcn_global_load_lds(
      (const __attribute__((address_space(1))) unsigned int*)gptr,
      (__attribute__((address_space(3))) unsigned int*)ldsptr, 16, 0, 0);
}

__device__ __forceinline__ unsigned pack_bf16x2(float a, float b) {
  __hip_bfloat162 h = __float22bfloat162_rn(float2{a, b});  // v_cvt_pk_bf16_f32
  return *reinterpret_cast<unsigned*>(&h);                  // a in low 16 bits
}

// LDS byte swizzle: XOR byte bits [6:4] with [9:7]. 16-B-granule preserving
// involution. Verified r6: GEMM conflicts 3.5M -> 0.
__device__ __forceinline__ int swz_g(int b) { return b ^ (((b >> 7) & 7) << 4); }

// ---------------- fused conversion kernel (one launch, r16-verified) ----------------
// blocks [0, 3072):      x [8192][768] fp32 -> bf16 flat (8 elem/thread)
// blocks [3072, 4800):   w_qkv [768][2304] -> wqkvT [2304][768] bf16 (transpose)
// blocks [4800, 5376):   w_proj [768][768] -> wprojT [768][768] bf16 (transpose)

__global__ void k_cvt_all(const float* __restrict__ x, __hip_bfloat16* __restrict__ xbf,
                          const float* __restrict__ wqkv, __hip_bfloat16* __restrict__ wqkvT,
                          const float* __restrict__ wproj, __hip_bfloat16* __restrict__ wprojT) {
  __shared__ float tile[32][33];
  int blk = blockIdx.x;
  if (blk < 3072) {
    int i = (blk * 256 + threadIdx.x) * 8;
    float4 a = *(const float4*)(x + i);
    float4 b = *(const float4*)(x + i + 4);
    union { __hip_bfloat16 h[8]; uint4 u; } r;
    r.h[0] = __float2bfloat16(a.x); r.h[1] = __float2bfloat16(a.y);
    r.h[2] = __float2bfloat16(a.z); r.h[3] = __float2bfloat16(a.w);
    r.h[4] = __float2bfloat16(b.x); r.h[5] = __float2bfloat16(b.y);
    r.h[6] = __float2bfloat16(b.z); r.h[7] = __float2bfloat16(b.w);
    *(uint4*)(xbf + i) = r.u;
    return;
  }
  blk -= 3072;
  const int kx = blk % 24;        // K-tile (768/32)
  const int ny = blk / 24;        // N-tile: 0..71 qkv, 72..95 proj
  const float* in;
  __hip_bfloat16* out;
  int N, n0;
  if (ny < 72) { in = wqkv;  out = wqkvT;  N = N3D; n0 = ny * 32; }
  else         { in = wproj; out = wprojT; N = ND;  n0 = (ny - 72) * 32; }
  const int k0 = kx * 32;
  const int r = threadIdx.x >> 5;   // 0..7
  const int c = threadIdx.x & 31;   // 0..31
#pragma unroll
  for (int i = 0; i < 4; ++i)
    tile[r + 8 * i][c] = in[(size_t)(k0 + r + 8 * i) * N + n0 + c];
  __syncthreads();
#pragma unroll
  for (int i = 0; i < 4; ++i)
    out[(size_t)(n0 + r + 8 * i) * 768 + k0 + c] = __float2bfloat16(tile[c][r + 8 * i]);
}

// ---------------- shared GEMM mainloop (r10/r12-verified: qkv 54.0-54.2 us) ----------------
// 128x128 tile, BK=64 (12 K-steps), 4 waves. TWO LDS buffers of 32 KB.
// Per K-step: vmcnt(8) -> barrier A -> 16 ds_read_b128 -> lgkmcnt(0) ->
// barrier B -> STAGE(kt+2) into retired buf -> 32 MFMA. Counted vmcnt
// never drained mid-loop; peeled final iteration drains vmcnt(0).

__device__ __forceinline__ void gemm_mainloop(const __hip_bfloat16* __restrict__ A,
                                              const __hip_bfloat16* __restrict__ BT,
                                              int m0, int n0, char* Ls,
                                              f32x4 acc[4][4]) {
  const int tid = threadIdx.x;
  const int wid = tid >> 6, lane = tid & 63;
  const int wm = wid >> 1, wn = wid & 1;
  const int lrow = lane & 15, lk = lane >> 4;
  constexpr int K = 768, NKT = K / 64;   // 12 K-steps

  int aoff[4][2], boff[4][2];
#pragma unroll
  for (int i = 0; i < 4; ++i)
#pragma unroll
    for (int kh = 0; kh < 2; ++kh) {
      aoff[i][kh] = swz_g((wm * 64 + i * 16 + lrow) * 128 + kh * 64 + lk * 16);
      boff[i][kh] = swz_g((wn * 64 + i * 16 + lrow) * 128 + kh * 64 + lk * 16);
    }

#define STAGE_G(kt, bi)                                                  \
  {                                                                      \
    const int k0s = (kt) * 64;                                           \
    char* dst = Ls + (bi) * 32768;                                       \
    _Pragma("unroll")                                                    \
    for (int t = 0; t < 4; ++t) {                                        \
      const int L = t * 4096 + tid * 16;   /* linear dest byte */        \
      const int lb = swz_g(L);             /* logical byte */            \
      const int mr = lb >> 7;              /* tile row (128 B/row) */    \
      const int kk = (lb & 127) >> 1;      /* bf16 col within row */     \
      gload_lds16(A + (size_t)(m0 + mr) * K + k0s + kk, dst + L);        \
      gload_lds16(BT + (size_t)(n0 + mr) * K + k0s + kk,                 \
                  dst + 16384 + L);                                      \
    }                                                                    \
  }

  STAGE_G(0, 0);
  STAGE_G(1, 1);            // 16 loads/thread outstanding

#pragma unroll 2
  for (int kt = 0; kt < NKT - 1; ++kt) {
    asm volatile("s_waitcnt vmcnt(8)" ::: "memory");   // tile kt (own loads) done
    __builtin_amdgcn_s_barrier();                      // A: whole tile kt visible

    const char* buf = Ls + (kt & 1) * 32768;
    short8 af[4][2], bf[4][2];
#pragma unroll
    for (int i = 0; i < 4; ++i)
#pragma unroll
      for (int kh = 0; kh < 2; ++kh) {
        af[i][kh] = *(const short8*)(buf + aoff[i][kh]);
        bf[i][kh] = *(const short8*)(buf + 16384 + boff[i][kh]);
      }

    asm volatile("s_waitcnt lgkmcnt(0)" ::: "memory"); // my reads complete
    __builtin_amdgcn_s_barrier();                      // B: everyone's reads done

    if (kt + 2 < NKT) STAGE_G(kt + 2, kt & 1);         // overwrite tile kt's buf

#pragma unroll
    for (int kh = 0; kh < 2; ++kh)
#pragma unroll
      for (int mi = 0; mi < 4; ++mi)
#pragma unroll
        for (int ni = 0; ni < 4; ++ni)
          acc[mi][ni] = MFMA_BF16(af[mi][kh], bf[ni][kh], acc[mi][ni]);
  }

  // peeled final iteration: only tile NKT-1 in flight -> full drain
  asm volatile("s_waitcnt vmcnt(0)" ::: "memory");
  __builtin_amdgcn_s_barrier();
  {
    const char* buf = Ls + ((NKT - 1) & 1) * 32768;
    short8 af[4][2], bf[4][2];
#pragma unroll
    for (int i = 0; i < 4; ++i)
#pragma unroll
      for (int kh = 0; kh < 2; ++kh) {
        af[i][kh] = *(const short8*)(buf + aoff[i][kh]);
        bf[i][kh] = *(const short8*)(buf + 16384 + boff[i][kh]);
      }
#pragma unroll
    for (int kh = 0; kh < 2; ++kh)
#pragma unroll
      for (int mi = 0; mi < 4; ++mi)
#pragma unroll
        for (int ni = 0; ni < 4; ++ni)
          acc[mi][ni] = MFMA_BF16(af[mi][kh], bf[ni][kh], acc[mi][ni]);
  }
#undef STAGE_G
}

// ---------------- QKV GEMM: C[8192][2304] = x@Wqkv + b; scatter to q/k/vT ----------------

__launch_bounds__(256)
__global__ void k_qkv_gemm(const __hip_bfloat16* __restrict__ A,
                           const __hip_bfloat16* __restrict__ BT,
                           const float* __restrict__ bias,
                           __hip_bfloat16* __restrict__ q_ws,   // [96][1024][64], pre-scaled
                           __hip_bfloat16* __restrict__ k_ws,   // [96][1024][64]
                           __hip_bfloat16* __restrict__ v_ws) { // [96][64][1024] (V^T)
  __shared__ char Ls[2 * 32768];
  const int mt = blockIdx.x & 63, nt = blockIdx.x >> 6;
  const int m0 = mt * 128, n0 = nt * 128;
  const int wid = threadIdx.x >> 6, lane = threadIdx.x & 63;
  const int wm = wid >> 1, wn = wid & 1;
  const int lrow = lane & 15, lk = lane >> 4;

  f32x4 acc[4][4] = {};
  gemm_mainloop(A, BT, m0, n0, Ls, acc);

  // each 128-wide N-tile lies entirely within q, k, or v (768 % 128 == 0)
  const int which = n0 / ND;
#pragma unroll
  for (int ni = 0; ni < 4; ++ni) {
    const int n = n0 + wn * 64 + ni * 16 + lrow;
    const float bv = bias[n];
    const int hh = (n % ND) >> 6;
    const int hd = n & 63;
#pragma unroll
    for (int mi = 0; mi < 4; ++mi) {
      const int mbase = m0 + wm * 64 + mi * 16 + lk * 4;
#pragma unroll
      for (int i = 0; i < 4; ++i) {
        const int m = mbase + i;
        const float v = acc[mi][ni][i] + bv;
        const int b = m >> 10, p = m & 1023;
        const int bh = b * NH + hh;
        if (which == 0)      q_ws[((size_t)bh * NP + p) * NHD + hd] = __float2bfloat16(v * QSCALE);
        else if (which == 1) k_ws[((size_t)bh * NP + p) * NHD + hd] = __float2bfloat16(v);
        else                 v_ws[((size_t)bh * NHD + hd) * NP + p] = __float2bfloat16(v);
      }
    }
  }
}

// ---------------- attention (r8-verified: 53.4 us) ----------------
// 1 block = (bh, 128 q-rows), 4 waves x 32 q-rows (two 16-row groups/wave).
// K/V chunks (64 keys) double-buffered in LDS (XOR-swizzled, rule 21);
// K-frags and V-frags loaded once per wave, reused by both q-groups.
// Grid = 768 blocks = exact capacity (3/CU); XCD-chunked: each XCD owns 12
// whole heads. Swapped QK^T: lane holds P for q-row = lrow, 4 keys.

#define KVBLK 64

__launch_bounds__(256)
__global__ void k_attn(const __hip_bfloat16* __restrict__ q_ws,
                       const __hip_bfloat16* __restrict__ k_ws,
                       const __hip_bfloat16* __restrict__ v_ws,  // [bh][64][1024]
                       float* __restrict__ wavg_f32,             // [8][1024][768]
                       __hip_bfloat16* __restrict__ wavg_bf) {
  // [2][K 8KB + V^T 8KB] dbuf + 4 waves x 32 rows x 144 B pbuf = 50 KB
  __shared__ char smem[2 * 16384 + 4 * 4608];
  const int bid = blockIdx.x;                       // 768 = 96 bh x 8 qb
  const int wg = (bid & 7) * 96 + (bid >> 3);       // XCD-chunk: 96 wgs/XCD
  const int bh = wg >> 3, qb = wg & 7;
  const int tid = threadIdx.x;
  const int wid = tid >> 6, lane = tid & 63;
  const int lrow = lane & 15, lk = lane >> 4;
  const int q0 = qb * 128 + wid * 32;
  char* pbuf = smem + 32768 + wid * 4608;           // 32 rows x 144 B

  const __hip_bfloat16* Qb = q_ws + (size_t)bh * NP * NHD;
  const __hip_bfloat16* Kb = k_ws + (size_t)bh * NP * NHD;
  const __hip_bfloat16* Vb = v_ws + (size_t)bh * NHD * NP;

  // Q fragments, two 16-row groups (pre-scaled by QSCALE at QKV epilogue)
  short8 qf[2][2];
#pragma unroll
  for (int g = 0; g < 2; ++g) {
    qf[g][0] = *(const short8*)(Qb + (size_t)(q0 + g * 16 + lrow) * NHD + lk * 8);
    qf[g][1] = *(const short8*)(Qb + (size_t)(q0 + g * 16 + lrow) * NHD + 32 + lk * 8);
  }

  f32x4 acc[2][4] = {};          // [group][hd-tile], 16 q x 16 hd each
  float dsum[2] = {0.f, 0.f};    // per-lane denom partial for q = lrow (group g)

#define STAGE(buf, key0)                                                          \
  {                                                                               \
    _Pragma("unroll")                                                             \
    for (int p = 0; p < 2; ++p) {                                                 \
      const int L = p * 4096 + tid * 16;                                          \
      const int r = L >> 7;                                                       \
      const int cb = L & 127;                                                     \
      const int sc = (cb ^ ((r & 7) << 4)) >> 1;  /* swizzled element col */      \
      gload_lds16(Kb + (size_t)((key0) + r) * NHD + sc, (buf) + L);               \
      gload_lds16(Vb + (size_t)r * NP + (key0) + sc, (buf) + 8192 + L);           \
    }                                                                             \
  }

  char* cur = smem;
  char* nxt = smem + 16384;
  STAGE(cur, 0);
  __syncthreads();   // drains vmcnt(0)

  for (int kc = 0; kc < NP / KVBLK; ++kc) {
    if (kc < NP / KVBLK - 1) STAGE(nxt, (kc + 1) * KVBLK);

    char* Ks = cur;
    char* Vs = cur + 8192;

    // swapped QK^T: s[g][kt] = S[key = kt*16 + lk*4 + i][q = g*16 + lrow]
    // K-frags read once, used by both groups.
    f32x4 s[2][4];
    __builtin_amdgcn_s_setprio(1);
#pragma unroll
    for (int kt = 0; kt < 4; ++kt) {
      const int row = kt * 16 + lrow;
      const int sw = (row & 7) << 4;
      short8 klo = *(const short8*)(Ks + row * 128 + ((lk * 16) ^ sw));
      short8 khi = *(const short8*)(Ks + row * 128 + ((64 + lk * 16) ^ sw));
      f32x4 z = {0.f, 0.f, 0.f, 0.f};
      s[0][kt] = MFMA_BF16(klo, qf[0][0], z);
      s[0][kt] = MFMA_BF16(khi, qf[0][1], s[0][kt]);
      s[1][kt] = MFMA_BF16(klo, qf[1][0], z);
      s[1][kt] = MFMA_BF16(khi, qf[1][1], s[1][kt]);
    }
    __builtin_amdgcn_s_setprio(0);

    // P = exp2(S); pack key pairs in-lane; write P[q][keys] at identity layout
#pragma unroll
    for (int g = 0; g < 2; ++g)
#pragma unroll
      for (int kt = 0; kt < 4; ++kt) {
        const float p0 = __builtin_amdgcn_exp2f(s[g][kt][0]);
        const float p1 = __builtin_amdgcn_exp2f(s[g][kt][1]);
        const float p2 = __builtin_amdgcn_exp2f(s[g][kt][2]);
        const float p3 = __builtin_amdgcn_exp2f(s[g][kt][3]);
        dsum[g] += (p0 + p1) + (p2 + p3);
        uint2 w;
        w.x = pack_bf16x2(p0, p1);
        w.y = pack_bf16x2(p2, p3);
        *(uint2*)(pbuf + (g * 16 + lrow) * 144 + kt * 32 + lk * 8) = w;
      }

    // PV: V-frags read once, used by both groups. D[m=q'][n=hd].
    __builtin_amdgcn_s_setprio(1);
#pragma unroll
    for (int kh = 0; kh < 2; ++kh) {
      short8 a20 = *(const short8*)(pbuf + lrow * 144 + kh * 64 + lk * 16);
      short8 a21 = *(const short8*)(pbuf + (16 + lrow) * 144 + kh * 64 + lk * 16);
#pragma unroll
      for (int hdt = 0; hdt < 4; ++hdt) {
        const int row = hdt * 16 + lrow;
        short8 vf = *(const short8*)(Vs + row * 128 +
                                     ((kh * 64 + lk * 16) ^ ((row & 7) << 4)));
        acc[0][hdt] = MFMA_BF16(a20, vf, acc[0][hdt]);
        acc[1][hdt] = MFMA_BF16(a21, vf, acc[1][hdt]);
      }
    }
    __builtin_amdgcn_s_setprio(0);

    __syncthreads();   // drains prefetch vmcnt + readers done before overwrite
    char* t = cur; cur = nxt; nxt = t;
  }

  const int b = bh / NH, hh = bh % NH;
#pragma unroll
  for (int g = 0; g < 2; ++g) {
    // combine the 4 lk-lanes holding q = lrow partials: xor 16, 32
    float ds = dsum[g];
    ds += __shfl_xor(ds, 16);
    ds += __shfl_xor(ds, 32);
    float rd[4];
#pragma unroll
    for (int i = 0; i < 4; ++i) rd[i] = 1.0f / __shfl(ds, lk * 4 + i, 16);

#pragma unroll
    for (int hdt = 0; hdt < 4; ++hdt) {
#pragma unroll
      for (int i = 0; i < 4; ++i) {
        const int qq = q0 + g * 16 + lk * 4 + i;
        const int col = hh * NHD + hdt * 16 + lrow;
        const float val = acc[g][hdt][i] * rd[i];
        const size_t o = ((size_t)b * NP + qq) * ND + col;
        wavg_f32[o] = val;
        wavg_bf[o] = __float2bfloat16(val);
      }
    }
  }
#undef STAGE
}

// ---------------- proj GEMM: out[8192][768] = wavg@Wproj + b (fp32 out) ----------------

__launch_bounds__(256)
__global__ void k_proj_gemm(const __hip_bfloat16* __restrict__ A,
                            const __hip_bfloat16* __restrict__ BT,
                            const float* __restrict__ bias,
                            float* __restrict__ C) {
  __shared__ char Ls[2 * 32768];
  const int mt = blockIdx.x & 63, nt = blockIdx.x >> 6;
  const int m0 = mt * 128, n0 = nt * 128;
  const int wid = threadIdx.x >> 6, lane = threadIdx.x & 63;
  const int wm = wid >> 1, wn = wid & 1;
  const int lrow = lane & 15, lk = lane >> 4;

  f32x4 acc[4][4] = {};
  gemm_mainloop(A, BT, m0, n0, Ls, acc);

#pragma unroll
  for (int ni = 0; ni < 4; ++ni) {
    const int n = n0 + wn * 64 + ni * 16 + lrow;
    const float bv = bias[n];
#pragma unroll
    for (int mi = 0; mi < 4; ++mi) {
      const int mbase = m0 + wm * 64 + mi * 16 + lk * 4;
#pragma unroll
      for (int i = 0; i < 4; ++i)
        C[(size_t)(mbase + i) * ND + n] = acc[mi][ni][i] + bv;
    }
  }
}

// ---------------- launch ----------------

extern "C" void kernel_launch(void* const* d_in, const int* in_sizes, int n_in,
                              void* d_out, int out_size, void* d_ws, size_t ws_size,
                              hipStream_t stream) {
  const float* x      = (const float*)d_in[0];
  const float* w_qkv  = (const float*)d_in[1];
  const float* b_qkv  = (const float*)d_in[2];
  const float* w_proj = (const float*)d_in[3];
  const float* b_proj = (const float*)d_in[4];
  float* out = (float*)d_out;
  float* wavg_out = out + OUT_HALF;

  char* ws = (char*)d_ws;
  // layout (bytes): x_bf16 / wavg_bf16 share (x dead before wavg written)
  __hip_bfloat16* xbf    = (__hip_bfloat16*)(ws);                 // 12,582,912
  __hip_bfloat16* wqkvT  = (__hip_bfloat16*)(ws + 12582912);      //  3,538,944
  __hip_bfloat16* wprojT = (__hip_bfloat16*)(ws + 16121856);      //  1,179,648
  __hip_bfloat16* q_ws   = (__hip_bfloat16*)(ws + 17301504);      // 12,582,912
  __hip_bfloat16* k_ws   = (__hip_bfloat16*)(ws + 29884416);      // 12,582,912
  __hip_bfloat16* v_ws   = (__hip_bfloat16*)(ws + 42467328);      // 12,582,912
  __hip_bfloat16* wavg_bf = xbf;                                  // total 55,050,240 B

  // fused: x-convert (3072 blocks) + wqkv transpose (1728) + wproj transpose (576)
  k_cvt_all<<<3072 + 24 * 96, 256, 0, stream>>>(x, xbf, w_qkv, wqkvT, w_proj, wprojT);
  k_qkv_gemm<<<(NTOK / 128) * (N3D / 128), 256, 0, stream>>>(xbf, wqkvT, b_qkv,
                                                             q_ws, k_ws, v_ws);
  k_attn<<<(NP / 128) * (NB * NH), 256, 0, stream>>>(q_ws, k_ws, v_ws, wavg_out, wavg_bf);
  k_proj_gemm<<<(NTOK / 128) * (ND / 128), 256, 0, stream>>>(wavg_bf, wprojT, b_proj, out);
}